// Round 1
// baseline (1699.453 us; speedup 1.0000x reference)
//
#include <hip/hip_runtime.h>
#include <hip/hip_bf16.h>
#include <math.h>

// Problem constants
#define B_SZ 4
#define L_SZ 8192
#define DM 512           // D_MODEL
#define DMEM 512         // D_MEM
#define M1 (B_SZ * (L_SZ - 1))   // 32764 rows for the av GEMM
#define M2 (B_SZ * L_SZ)         // 32768 rows for GEMM2/3

// ---------------------------------------------------------------------------
// GEMM1 (grouped x4) fused with NRU combine:
//   ms_inp[m][n] = (av0)*(av1) - (av2)*(av3),  av_g = dot(x[row(m)], W_av[n+512g]) + b_av
// Tile: BM=128, BN=64, BK=16; block 16x16, per-thread 8x4 per group, 4 groups.
// ---------------------------------------------------------------------------
__global__ __launch_bounds__(256) void gemm_av_fused(
    const float* __restrict__ x, const float* __restrict__ Wav,
    const float* __restrict__ bav, float* __restrict__ ms_inp)
{
    __shared__ float As[16][132];       // [k][m], padded
    __shared__ float Bs[4][16][68];     // [g][k][n], padded

    const int tx = threadIdx.x;         // 0..15 (n)
    const int ty = threadIdx.y;         // 0..15 (m)
    const int tid = ty * 16 + tx;
    const int bm = blockIdx.x * 128;
    const int bn = blockIdx.y * 64;

    const int ar = tid >> 2;            // 0..63
    const int ak = (tid & 3) * 4;       // 0,4,8,12

    float acc[4][8][4];
    #pragma unroll
    for (int g = 0; g < 4; ++g)
        #pragma unroll
        for (int i = 0; i < 8; ++i)
            #pragma unroll
            for (int j = 0; j < 4; ++j) acc[g][i][j] = 0.f;

    for (int k0 = 0; k0 < DM; k0 += 16) {
        // ---- stage A tile (128 rows x 16 k) ----
        #pragma unroll
        for (int i = 0; i < 2; ++i) {
            int m = bm + ar + i * 64;
            int mg = m < M1 ? m : (M1 - 1);
            int row = mg + mg / (L_SZ - 1);     // skip last l of each batch
            float4 v = *(const float4*)(x + (size_t)row * DM + k0 + ak);
            As[ak + 0][ar + i * 64] = v.x;
            As[ak + 1][ar + i * 64] = v.y;
            As[ak + 2][ar + i * 64] = v.z;
            As[ak + 3][ar + i * 64] = v.w;
        }
        // ---- stage B tiles (4 groups x 64 rows x 16 k) ----
        #pragma unroll
        for (int g = 0; g < 4; ++g) {
            int n = bn + ar;
            float4 v = *(const float4*)(Wav + (size_t)(n + g * 512) * DM + k0 + ak);
            Bs[g][ak + 0][ar] = v.x;
            Bs[g][ak + 1][ar] = v.y;
            Bs[g][ak + 2][ar] = v.z;
            Bs[g][ak + 3][ar] = v.w;
        }
        __syncthreads();

        #pragma unroll
        for (int kk = 0; kk < 16; ++kk) {
            float4 a0 = *(const float4*)&As[kk][ty * 8];
            float4 a1 = *(const float4*)&As[kk][ty * 8 + 4];
            float a[8] = {a0.x, a0.y, a0.z, a0.w, a1.x, a1.y, a1.z, a1.w};
            #pragma unroll
            for (int g = 0; g < 4; ++g) {
                float4 bv = *(const float4*)&Bs[g][kk][tx * 4];
                float bb[4] = {bv.x, bv.y, bv.z, bv.w};
                #pragma unroll
                for (int i = 0; i < 8; ++i)
                    #pragma unroll
                    for (int j = 0; j < 4; ++j)
                        acc[g][i][j] = fmaf(a[i], bb[j], acc[g][i][j]);
            }
        }
        __syncthreads();
    }

    // ---- epilogue: combine 4 groups -> ms_inp ----
    const int n0 = bn + tx * 4;
    float b0[4], b1[4], b2[4], b3[4];
    #pragma unroll
    for (int j = 0; j < 4; ++j) {
        b0[j] = bav[n0 + j];
        b1[j] = bav[n0 + j + 512];
        b2[j] = bav[n0 + j + 1024];
        b3[j] = bav[n0 + j + 1536];
    }
    #pragma unroll
    for (int i = 0; i < 8; ++i) {
        int m = bm + ty * 8 + i;
        if (m >= M1) break;
        float4 r;
        float v[4];
        #pragma unroll
        for (int j = 0; j < 4; ++j) {
            float a0 = acc[0][i][j] + b0[j];
            float a1 = acc[1][i][j] + b1[j];
            float a2 = acc[2][i][j] + b2[j];
            float a3 = acc[3][i][j] + b3[j];
            v[j] = a0 * a1 - a2 * a3;
        }
        r.x = v[0]; r.y = v[1]; r.z = v[2]; r.w = v[3];
        *(float4*)(ms_inp + (size_t)m * DMEM + n0) = r;
    }
}

// ---------------------------------------------------------------------------
// Scan pass 1: per-chunk sums. Chunks of 128 along l (64 chunks cover 8191).
// ---------------------------------------------------------------------------
__global__ __launch_bounds__(256) void scan_pass1(
    const float* __restrict__ ms_inp, float* __restrict__ csum)
{
    int c = blockIdx.x, b = blockIdx.y;
    int l0 = c * 128;
    int len = min(128, (L_SZ - 1) - l0);
    int t = threadIdx.x;            // 0..255 -> float2 over 512 d
    const float2* p = (const float2*)(ms_inp + ((size_t)b * (L_SZ - 1) + l0) * DMEM) + t;
    float2 s = make_float2(0.f, 0.f);
    for (int i = 0; i < len; ++i) {
        float2 v = p[(size_t)i * 256];
        s.x += v.x; s.y += v.y;
    }
    ((float2*)(csum + ((size_t)b * 64 + c) * DMEM))[t] = s;
}

// ---------------------------------------------------------------------------
// Scan pass 2: exclusive scan of the 64 chunk sums per (b,d).
// ---------------------------------------------------------------------------
__global__ __launch_bounds__(256) void scan_pass2(float* __restrict__ csum)
{
    int idx = blockIdx.x * 256 + threadIdx.x;   // 0..2047
    int b = idx >> 9, d = idx & 511;
    float run = 0.f;
    float* p = csum + (size_t)b * 64 * DMEM + d;
    for (int c = 0; c < 64; ++c) {
        float t = p[(size_t)c * DMEM];
        p[(size_t)c * DMEM] = run;
        run += t;
    }
}

// ---------------------------------------------------------------------------
// Scan pass 3: chunk-local inclusive scan + chunk offset -> ms[b, l, d]
// ms[b,0,:] = 0 ; ms[b,l,:] = sum_{i<l} ms_inp[b,i,:]
// ---------------------------------------------------------------------------
__global__ __launch_bounds__(256) void scan_pass3(
    const float* __restrict__ ms_inp, const float* __restrict__ csum,
    float* __restrict__ ms)
{
    int c = blockIdx.x, b = blockIdx.y;
    int l0 = c * 128;
    int len = min(128, (L_SZ - 1) - l0);
    int t = threadIdx.x;
    float2 run = ((const float2*)(csum + ((size_t)b * 64 + c) * DMEM))[t];
    const float2* p = (const float2*)(ms_inp + ((size_t)b * (L_SZ - 1) + l0) * DMEM) + t;
    float2* q = (float2*)(ms + ((size_t)b * L_SZ + l0 + 1) * DMEM) + t;
    if (c == 0)
        ((float2*)(ms + (size_t)b * L_SZ * DMEM))[t] = make_float2(0.f, 0.f);
    for (int i = 0; i < len; ++i) {
        float2 v = p[(size_t)i * 256];
        run.x += v.x; run.y += v.y;
        q[(size_t)i * 256] = run;
    }
}

// ---------------------------------------------------------------------------
// GEMM2 fused with exact GELU: y[m][n] = gelu( dot(concat(x,ms)[m], W_go[n]) + b_go[n] )
// K=1024 (first 512 from x, next 512 from ms). Tile 128x128, BK=16, 8x8/thread.
// ---------------------------------------------------------------------------
__global__ __launch_bounds__(256) void gemm_go_gelu(
    const float* __restrict__ x, const float* __restrict__ ms,
    const float* __restrict__ Wgo, const float* __restrict__ bgo,
    float* __restrict__ y)
{
    __shared__ float As[16][132];
    __shared__ float Bs[16][132];

    const int tx = threadIdx.x, ty = threadIdx.y;
    const int tid = ty * 16 + tx;
    const int bm = blockIdx.x * 128;
    const int bn = blockIdx.y * 128;
    const int ar = tid >> 2;
    const int ak = (tid & 3) * 4;

    float acc[8][8];
    #pragma unroll
    for (int i = 0; i < 8; ++i)
        #pragma unroll
        for (int j = 0; j < 8; ++j) acc[i][j] = 0.f;

    for (int k0 = 0; k0 < 1024; k0 += 16) {
        const float* src = (k0 < 512) ? x : ms;
        const int col = (k0 < 512) ? k0 : (k0 - 512);
        #pragma unroll
        for (int i = 0; i < 2; ++i) {
            int m = bm + ar + i * 64;
            float4 v = *(const float4*)(src + (size_t)m * DM + col + ak);
            As[ak + 0][ar + i * 64] = v.x;
            As[ak + 1][ar + i * 64] = v.y;
            As[ak + 2][ar + i * 64] = v.z;
            As[ak + 3][ar + i * 64] = v.w;
        }
        #pragma unroll
        for (int i = 0; i < 2; ++i) {
            int n = bn + ar + i * 64;
            float4 v = *(const float4*)(Wgo + (size_t)n * 1024 + k0 + ak);
            Bs[ak + 0][ar + i * 64] = v.x;
            Bs[ak + 1][ar + i * 64] = v.y;
            Bs[ak + 2][ar + i * 64] = v.z;
            Bs[ak + 3][ar + i * 64] = v.w;
        }
        __syncthreads();

        #pragma unroll
        for (int kk = 0; kk < 16; ++kk) {
            float4 a0 = *(const float4*)&As[kk][ty * 8];
            float4 a1 = *(const float4*)&As[kk][ty * 8 + 4];
            float4 c0 = *(const float4*)&Bs[kk][tx * 8];
            float4 c1 = *(const float4*)&Bs[kk][tx * 8 + 4];
            float a[8] = {a0.x, a0.y, a0.z, a0.w, a1.x, a1.y, a1.z, a1.w};
            float bb[8] = {c0.x, c0.y, c0.z, c0.w, c1.x, c1.y, c1.z, c1.w};
            #pragma unroll
            for (int i = 0; i < 8; ++i)
                #pragma unroll
                for (int j = 0; j < 8; ++j)
                    acc[i][j] = fmaf(a[i], bb[j], acc[i][j]);
        }
        __syncthreads();
    }

    const int n0 = bn + tx * 8;
    float bias[8];
    #pragma unroll
    for (int j = 0; j < 8; ++j) bias[j] = bgo[n0 + j];
    #pragma unroll
    for (int i = 0; i < 8; ++i) {
        int m = bm + ty * 8 + i;
        float v[8];
        #pragma unroll
        for (int j = 0; j < 8; ++j) {
            float t = acc[i][j] + bias[j];
            v[j] = 0.5f * t * (1.0f + erff(t * 0.70710678118654752f));
        }
        *(float4*)(y + (size_t)m * DM + n0)     = make_float4(v[0], v[1], v[2], v[3]);
        *(float4*)(y + (size_t)m * DM + n0 + 4) = make_float4(v[4], v[5], v[6], v[7]);
    }
}

// ---------------------------------------------------------------------------
// GEMM3 (grouped x2) fused with GLU:
//   z_g = dot(y[m], W_out[n+512g]) + b_out[n+512g];  out = z0 * sigmoid(z1)
// Tile 128x64, BK=16, per-thread 8x4 per group, 2 groups.
// ---------------------------------------------------------------------------
__global__ __launch_bounds__(256) void gemm_out_glu(
    const float* __restrict__ y, const float* __restrict__ Wout,
    const float* __restrict__ bout, float* __restrict__ out)
{
    __shared__ float As[16][132];
    __shared__ float Bs[2][16][68];

    const int tx = threadIdx.x, ty = threadIdx.y;
    const int tid = ty * 16 + tx;
    const int bm = blockIdx.x * 128;
    const int bn = blockIdx.y * 64;
    const int ar = tid >> 2;
    const int ak = (tid & 3) * 4;

    float acc[2][8][4];
    #pragma unroll
    for (int g = 0; g < 2; ++g)
        #pragma unroll
        for (int i = 0; i < 8; ++i)
            #pragma unroll
            for (int j = 0; j < 4; ++j) acc[g][i][j] = 0.f;

    for (int k0 = 0; k0 < DM; k0 += 16) {
        #pragma unroll
        for (int i = 0; i < 2; ++i) {
            int m = bm + ar + i * 64;
            float4 v = *(const float4*)(y + (size_t)m * DM + k0 + ak);
            As[ak + 0][ar + i * 64] = v.x;
            As[ak + 1][ar + i * 64] = v.y;
            As[ak + 2][ar + i * 64] = v.z;
            As[ak + 3][ar + i * 64] = v.w;
        }
        #pragma unroll
        for (int g = 0; g < 2; ++g) {
            int n = bn + ar;
            float4 v = *(const float4*)(Wout + (size_t)(n + g * 512) * DM + k0 + ak);
            Bs[g][ak + 0][ar] = v.x;
            Bs[g][ak + 1][ar] = v.y;
            Bs[g][ak + 2][ar] = v.z;
            Bs[g][ak + 3][ar] = v.w;
        }
        __syncthreads();

        #pragma unroll
        for (int kk = 0; kk < 16; ++kk) {
            float4 a0 = *(const float4*)&As[kk][ty * 8];
            float4 a1 = *(const float4*)&As[kk][ty * 8 + 4];
            float a[8] = {a0.x, a0.y, a0.z, a0.w, a1.x, a1.y, a1.z, a1.w};
            #pragma unroll
            for (int g = 0; g < 2; ++g) {
                float4 bv = *(const float4*)&Bs[g][kk][tx * 4];
                float bb[4] = {bv.x, bv.y, bv.z, bv.w};
                #pragma unroll
                for (int i = 0; i < 8; ++i)
                    #pragma unroll
                    for (int j = 0; j < 4; ++j)
                        acc[g][i][j] = fmaf(a[i], bb[j], acc[g][i][j]);
            }
        }
        __syncthreads();
    }

    const int n0 = bn + tx * 4;
    float bz0[4], bz1[4];
    #pragma unroll
    for (int j = 0; j < 4; ++j) {
        bz0[j] = bout[n0 + j];
        bz1[j] = bout[n0 + j + 512];
    }
    #pragma unroll
    for (int i = 0; i < 8; ++i) {
        int m = bm + ty * 8 + i;
        float v[4];
        #pragma unroll
        for (int j = 0; j < 4; ++j) {
            float z0 = acc[0][i][j] + bz0[j];
            float z1 = acc[1][i][j] + bz1[j];
            v[j] = z0 * (1.0f / (1.0f + expf(-z1)));
        }
        *(float4*)(out + (size_t)m * DM + n0) = make_float4(v[0], v[1], v[2], v[3]);
    }
}

// ---------------------------------------------------------------------------
extern "C" void kernel_launch(void* const* d_in, const int* in_sizes, int n_in,
                              void* d_out, int out_size, void* d_ws, size_t ws_size,
                              hipStream_t stream)
{
    const float* x    = (const float*)d_in[0];
    const float* Wav  = (const float*)d_in[1];
    const float* bav  = (const float*)d_in[2];
    const float* Wgo  = (const float*)d_in[3];
    const float* bgo  = (const float*)d_in[4];
    const float* Wout = (const float*)d_in[5];
    const float* bout = (const float*)d_in[6];
    float* out = (float*)d_out;

    char* ws = (char*)d_ws;
    const size_t R = 67108864;                 // 64 MiB region
    float* ms_inp = (float*)ws;                // [32764, 512]  (later reused as y)
    float* msbuf  = (float*)(ws + R);          // [32768, 512]
    float* csum   = (float*)(ws + 2 * R);      // [4, 64, 512]
    float* y      = ms_inp;                    // reuse after scan consumes ms_inp

    dim3 blk(16, 16);

    // 1) av GEMM + NRU combine -> ms_inp
    gemm_av_fused<<<dim3((M1 + 127) / 128, DMEM / 64), blk, 0, stream>>>(x, Wav, bav, ms_inp);
    // 2-4) chunked cumsum -> ms
    scan_pass1<<<dim3(64, B_SZ), 256, 0, stream>>>(ms_inp, csum);
    scan_pass2<<<8, 256, 0, stream>>>(csum);
    scan_pass3<<<dim3(64, B_SZ), 256, 0, stream>>>(ms_inp, csum, msbuf);
    // 5) SSM-in GEMM + GELU -> y  (reuses ms_inp region)
    gemm_go_gelu<<<dim3(M2 / 128, DM / 128), blk, 0, stream>>>(x, msbuf, Wgo, bgo, y);
    // 6) output GEMM + GLU -> out
    gemm_out_glu<<<dim3(M2 / 128, DM / 64), blk, 0, stream>>>(y, Wout, bout, out);
}

// Round 2
// 688.029 us; speedup vs baseline: 2.4700x; 2.4700x over previous
//
#include <hip/hip_runtime.h>
#include <hip/hip_bf16.h>
#include <math.h>

// Problem constants
#define B_SZ 4
#define L_SZ 8192
#define DM 512           // D_MODEL
#define DMEM 512         // D_MEM
#define M1 (B_SZ * (L_SZ - 1))   // 32764 rows for the av GEMM
#define M2 (B_SZ * L_SZ)         // 32768 rows for GEMM2/3

typedef __attribute__((ext_vector_type(8))) short bf16x8;
typedef __attribute__((ext_vector_type(4))) float f32x4;

// fp32 -> bf16 round-to-nearest-even, returned as bit pattern
__device__ __forceinline__ unsigned short f2bf(float f) {
    union { float f; unsigned u; } v; v.f = f;
    unsigned u = v.u;
    u += 0x7FFF + ((u >> 16) & 1);
    return (unsigned short)(u >> 16);
}
__device__ __forceinline__ float bf2f(unsigned short s) {
    union { unsigned u; float f; } v; v.u = ((unsigned)s) << 16;
    return v.f;
}
// split one float4 into bf16 hi and lo short4s
__device__ __forceinline__ void split4(float4 v, ushort4& h, ushort4& l) {
    h.x = f2bf(v.x); l.x = f2bf(v.x - bf2f(h.x));
    h.y = f2bf(v.y); l.y = f2bf(v.y - bf2f(h.y));
    h.z = f2bf(v.z); l.z = f2bf(v.z - bf2f(h.z));
    h.w = f2bf(v.w); l.w = f2bf(v.w - bf2f(h.w));
}

#define MFMA(a, b, c) __builtin_amdgcn_mfma_f32_16x16x32_bf16((a), (b), (c), 0, 0, 0)

// ---------------------------------------------------------------------------
// GEMM1 (grouped x4, split-bf16 MFMA) fused with NRU combine.
// BM=128, BN=32 (x4 groups), BK=32. 4 waves, each 32m x 32n x 4g.
// ---------------------------------------------------------------------------
__global__ __launch_bounds__(256) void gemm_av_mfma(
    const float* __restrict__ x, const float* __restrict__ Wav,
    const float* __restrict__ bav, float* __restrict__ ms_inp)
{
    __shared__ unsigned short Ah[128][40];
    __shared__ unsigned short Al[128][40];
    __shared__ unsigned short Bh[4][32][40];
    __shared__ unsigned short Bl[4][32][40];

    const int tid  = threadIdx.x;
    const int lane = tid & 63;
    const int w    = tid >> 6;          // wave 0..3
    const int wm   = w * 32;
    const int bm   = blockIdx.x * 128;
    const int bn   = blockIdx.y * 32;
    const int ln   = lane & 15;
    const int ko   = (lane >> 4) * 8;

    f32x4 acc[4][2][2];
    #pragma unroll
    for (int g = 0; g < 4; ++g)
        #pragma unroll
        for (int a = 0; a < 2; ++a)
            #pragma unroll
            for (int b = 0; b < 2; ++b) acc[g][a][b] = (f32x4){0.f, 0.f, 0.f, 0.f};

    for (int k0 = 0; k0 < DM; k0 += 32) {
        // ---- stage A (128x32 fp32 -> hi/lo bf16) ----
        #pragma unroll
        for (int i = 0; i < 4; ++i) {
            int s = tid + i * 256;
            int row = s >> 3, c = s & 7;
            int m = bm + row;
            int mg = m < M1 ? m : (M1 - 1);
            int xr = mg + mg / (L_SZ - 1);
            float4 v = *(const float4*)(x + (size_t)xr * DM + k0 + c * 4);
            ushort4 h, l; split4(v, h, l);
            *(ushort4*)&Ah[row][c * 4] = h;
            *(ushort4*)&Al[row][c * 4] = l;
        }
        // ---- stage B (4 x 32 x 32) ----
        #pragma unroll
        for (int i = 0; i < 4; ++i) {
            int s = tid + i * 256;
            int g = s >> 8, n = (s >> 3) & 31, c = s & 7;
            float4 v = *(const float4*)(Wav + (size_t)(g * 512 + bn + n) * DM + k0 + c * 4);
            ushort4 h, l; split4(v, h, l);
            *(ushort4*)&Bh[g][n][c * 4] = h;
            *(ushort4*)&Bl[g][n][c * 4] = l;
        }
        __syncthreads();

        bf16x8 ah[2], al[2];
        #pragma unroll
        for (int fm = 0; fm < 2; ++fm) {
            int r = wm + fm * 16 + ln;
            ah[fm] = *(const bf16x8*)&Ah[r][ko];
            al[fm] = *(const bf16x8*)&Al[r][ko];
        }
        #pragma unroll
        for (int g = 0; g < 4; ++g) {
            #pragma unroll
            for (int fn = 0; fn < 2; ++fn) {
                int nr = fn * 16 + ln;
                bf16x8 bh = *(const bf16x8*)&Bh[g][nr][ko];
                bf16x8 bl = *(const bf16x8*)&Bl[g][nr][ko];
                #pragma unroll
                for (int fm = 0; fm < 2; ++fm) {
                    acc[g][fm][fn] = MFMA(ah[fm], bh, acc[g][fm][fn]);
                    acc[g][fm][fn] = MFMA(ah[fm], bl, acc[g][fm][fn]);
                    acc[g][fm][fn] = MFMA(al[fm], bh, acc[g][fm][fn]);
                }
            }
        }
        __syncthreads();
    }

    // ---- epilogue: combine 4 groups -> ms_inp ----
    const int lm = (lane >> 4) * 4;
    #pragma unroll
    for (int fm = 0; fm < 2; ++fm) {
        #pragma unroll
        for (int fn = 0; fn < 2; ++fn) {
            int n = bn + fn * 16 + ln;
            float b0 = bav[n], b1 = bav[n + 512], b2 = bav[n + 1024], b3 = bav[n + 1536];
            #pragma unroll
            for (int i = 0; i < 4; ++i) {
                int m = bm + wm + fm * 16 + lm + i;
                if (m < M1) {
                    float a0 = acc[0][fm][fn][i] + b0;
                    float a1 = acc[1][fm][fn][i] + b1;
                    float a2 = acc[2][fm][fn][i] + b2;
                    float a3 = acc[3][fm][fn][i] + b3;
                    ms_inp[(size_t)m * DMEM + n] = a0 * a1 - a2 * a3;
                }
            }
        }
    }
}

// ---------------------------------------------------------------------------
// Scan pass 1: per-chunk sums. Chunks of 128 along l (64 chunks cover 8191).
// ---------------------------------------------------------------------------
__global__ __launch_bounds__(256) void scan_pass1(
    const float* __restrict__ ms_inp, float* __restrict__ csum)
{
    int c = blockIdx.x, b = blockIdx.y;
    int l0 = c * 128;
    int len = min(128, (L_SZ - 1) - l0);
    int t = threadIdx.x;
    const float2* p = (const float2*)(ms_inp + ((size_t)b * (L_SZ - 1) + l0) * DMEM) + t;
    float2 s = make_float2(0.f, 0.f);
    for (int i = 0; i < len; ++i) {
        float2 v = p[(size_t)i * 256];
        s.x += v.x; s.y += v.y;
    }
    ((float2*)(csum + ((size_t)b * 64 + c) * DMEM))[t] = s;
}

__global__ __launch_bounds__(256) void scan_pass2(float* __restrict__ csum)
{
    int idx = blockIdx.x * 256 + threadIdx.x;
    int b = idx >> 9, d = idx & 511;
    float run = 0.f;
    float* p = csum + (size_t)b * 64 * DMEM + d;
    for (int c = 0; c < 64; ++c) {
        float t = p[(size_t)c * DMEM];
        p[(size_t)c * DMEM] = run;
        run += t;
    }
}

__global__ __launch_bounds__(256) void scan_pass3(
    const float* __restrict__ ms_inp, const float* __restrict__ csum,
    float* __restrict__ ms)
{
    int c = blockIdx.x, b = blockIdx.y;
    int l0 = c * 128;
    int len = min(128, (L_SZ - 1) - l0);
    int t = threadIdx.x;
    float2 run = ((const float2*)(csum + ((size_t)b * 64 + c) * DMEM))[t];
    const float2* p = (const float2*)(ms_inp + ((size_t)b * (L_SZ - 1) + l0) * DMEM) + t;
    float2* q = (float2*)(ms + ((size_t)b * L_SZ + l0 + 1) * DMEM) + t;
    if (c == 0)
        ((float2*)(ms + (size_t)b * L_SZ * DMEM))[t] = make_float2(0.f, 0.f);
    for (int i = 0; i < len; ++i) {
        float2 v = p[(size_t)i * 256];
        run.x += v.x; run.y += v.y;
        q[(size_t)i * 256] = run;
    }
}

// ---------------------------------------------------------------------------
// GEMM2 (split-bf16 MFMA) + exact GELU. K=1024 (x || ms). BM=128, BN=128,
// BK=32. 4 waves (2x2), each 64m x 64n.
// ---------------------------------------------------------------------------
__global__ __launch_bounds__(256) void gemm_go_mfma(
    const float* __restrict__ x, const float* __restrict__ ms,
    const float* __restrict__ Wgo, const float* __restrict__ bgo,
    float* __restrict__ y)
{
    __shared__ unsigned short Ah[128][40];
    __shared__ unsigned short Al[128][40];
    __shared__ unsigned short Bh[128][40];
    __shared__ unsigned short Bl[128][40];

    const int tid  = threadIdx.x;
    const int lane = tid & 63;
    const int w    = tid >> 6;
    const int wm   = (w & 1) * 64;
    const int wn   = (w >> 1) * 64;
    const int bm   = blockIdx.x * 128;
    const int bn   = blockIdx.y * 128;
    const int ln   = lane & 15;
    const int ko   = (lane >> 4) * 8;

    f32x4 acc[4][4];
    #pragma unroll
    for (int a = 0; a < 4; ++a)
        #pragma unroll
        for (int b = 0; b < 4; ++b) acc[a][b] = (f32x4){0.f, 0.f, 0.f, 0.f};

    for (int k0 = 0; k0 < 1024; k0 += 32) {
        const float* src = (k0 < 512) ? x : ms;
        const int col = (k0 < 512) ? k0 : (k0 - 512);
        #pragma unroll
        for (int i = 0; i < 4; ++i) {
            int s = tid + i * 256;
            int row = s >> 3, c = s & 7;
            float4 v = *(const float4*)(src + (size_t)(bm + row) * DM + col + c * 4);
            ushort4 h, l; split4(v, h, l);
            *(ushort4*)&Ah[row][c * 4] = h;
            *(ushort4*)&Al[row][c * 4] = l;
        }
        #pragma unroll
        for (int i = 0; i < 4; ++i) {
            int s = tid + i * 256;
            int n = s >> 3, c = s & 7;
            float4 v = *(const float4*)(Wgo + (size_t)(bn + n) * 1024 + k0 + c * 4);
            ushort4 h, l; split4(v, h, l);
            *(ushort4*)&Bh[n][c * 4] = h;
            *(ushort4*)&Bl[n][c * 4] = l;
        }
        __syncthreads();

        bf16x8 ah[4], al[4];
        #pragma unroll
        for (int fm = 0; fm < 4; ++fm) {
            int r = wm + fm * 16 + ln;
            ah[fm] = *(const bf16x8*)&Ah[r][ko];
            al[fm] = *(const bf16x8*)&Al[r][ko];
        }
        #pragma unroll
        for (int fn = 0; fn < 4; ++fn) {
            int nr = wn + fn * 16 + ln;
            bf16x8 bh = *(const bf16x8*)&Bh[nr][ko];
            bf16x8 bl = *(const bf16x8*)&Bl[nr][ko];
            #pragma unroll
            for (int fm = 0; fm < 4; ++fm) {
                acc[fm][fn] = MFMA(ah[fm], bh, acc[fm][fn]);
                acc[fm][fn] = MFMA(ah[fm], bl, acc[fm][fn]);
                acc[fm][fn] = MFMA(al[fm], bh, acc[fm][fn]);
            }
        }
        __syncthreads();
    }

    const int lm = (lane >> 4) * 4;
    #pragma unroll
    for (int fm = 0; fm < 4; ++fm) {
        #pragma unroll
        for (int fn = 0; fn < 4; ++fn) {
            int n = bn + wn + fn * 16 + ln;
            float bias = bgo[n];
            #pragma unroll
            for (int i = 0; i < 4; ++i) {
                int m = bm + wm + fm * 16 + lm + i;
                float t = acc[fm][fn][i] + bias;
                y[(size_t)m * DM + n] = 0.5f * t * (1.0f + erff(t * 0.70710678118654752f));
            }
        }
    }
}

// ---------------------------------------------------------------------------
// GEMM3 (grouped x2, split-bf16 MFMA) + GLU. BM=128, BN=64 (x2 groups),
// BK=32. 4 waves (2x2), each 64m x 32n x 2g.
// ---------------------------------------------------------------------------
__global__ __launch_bounds__(256) void gemm_out_mfma(
    const float* __restrict__ y, const float* __restrict__ Wout,
    const float* __restrict__ bout, float* __restrict__ out)
{
    __shared__ unsigned short Ah[128][40];
    __shared__ unsigned short Al[128][40];
    __shared__ unsigned short Bh[2][64][40];
    __shared__ unsigned short Bl[2][64][40];

    const int tid  = threadIdx.x;
    const int lane = tid & 63;
    const int w    = tid >> 6;
    const int wm   = (w & 1) * 64;
    const int wn   = (w >> 1) * 32;
    const int bm   = blockIdx.x * 128;
    const int bn   = blockIdx.y * 64;
    const int ln   = lane & 15;
    const int ko   = (lane >> 4) * 8;

    f32x4 acc[2][4][2];
    #pragma unroll
    for (int g = 0; g < 2; ++g)
        #pragma unroll
        for (int a = 0; a < 4; ++a)
            #pragma unroll
            for (int b = 0; b < 2; ++b) acc[g][a][b] = (f32x4){0.f, 0.f, 0.f, 0.f};

    for (int k0 = 0; k0 < DM; k0 += 32) {
        #pragma unroll
        for (int i = 0; i < 4; ++i) {
            int s = tid + i * 256;
            int row = s >> 3, c = s & 7;
            float4 v = *(const float4*)(y + (size_t)(bm + row) * DM + k0 + c * 4);
            ushort4 h, l; split4(v, h, l);
            *(ushort4*)&Ah[row][c * 4] = h;
            *(ushort4*)&Al[row][c * 4] = l;
        }
        #pragma unroll
        for (int i = 0; i < 4; ++i) {
            int s = tid + i * 256;
            int g = s >> 9, n = (s >> 3) & 63, c = s & 7;
            float4 v = *(const float4*)(Wout + (size_t)(g * 512 + bn + n) * DM + k0 + c * 4);
            ushort4 h, l; split4(v, h, l);
            *(ushort4*)&Bh[g][n][c * 4] = h;
            *(ushort4*)&Bl[g][n][c * 4] = l;
        }
        __syncthreads();

        bf16x8 ah[4], al[4];
        #pragma unroll
        for (int fm = 0; fm < 4; ++fm) {
            int r = wm + fm * 16 + ln;
            ah[fm] = *(const bf16x8*)&Ah[r][ko];
            al[fm] = *(const bf16x8*)&Al[r][ko];
        }
        #pragma unroll
        for (int g = 0; g < 2; ++g) {
            #pragma unroll
            for (int fn = 0; fn < 2; ++fn) {
                int nr = wn + fn * 16 + ln;
                bf16x8 bh = *(const bf16x8*)&Bh[g][nr][ko];
                bf16x8 bl = *(const bf16x8*)&Bl[g][nr][ko];
                #pragma unroll
                for (int fm = 0; fm < 4; ++fm) {
                    acc[g][fm][fn] = MFMA(ah[fm], bh, acc[g][fm][fn]);
                    acc[g][fm][fn] = MFMA(ah[fm], bl, acc[g][fm][fn]);
                    acc[g][fm][fn] = MFMA(al[fm], bh, acc[g][fm][fn]);
                }
            }
        }
        __syncthreads();
    }

    const int lm = (lane >> 4) * 4;
    #pragma unroll
    for (int fm = 0; fm < 4; ++fm) {
        #pragma unroll
        for (int fn = 0; fn < 2; ++fn) {
            int n = bn + wn + fn * 16 + ln;
            float bz0 = bout[n], bz1 = bout[n + 512];
            #pragma unroll
            for (int i = 0; i < 4; ++i) {
                int m = bm + wm + fm * 16 + lm + i;
                float z0 = acc[0][fm][fn][i] + bz0;
                float z1 = acc[1][fm][fn][i] + bz1;
                out[(size_t)m * DM + n] = z0 * (1.0f / (1.0f + expf(-z1)));
            }
        }
    }
}

// ---------------------------------------------------------------------------
extern "C" void kernel_launch(void* const* d_in, const int* in_sizes, int n_in,
                              void* d_out, int out_size, void* d_ws, size_t ws_size,
                              hipStream_t stream)
{
    const float* x    = (const float*)d_in[0];
    const float* Wav  = (const float*)d_in[1];
    const float* bav  = (const float*)d_in[2];
    const float* Wgo  = (const float*)d_in[3];
    const float* bgo  = (const float*)d_in[4];
    const float* Wout = (const float*)d_in[5];
    const float* bout = (const float*)d_in[6];
    float* out = (float*)d_out;

    char* ws = (char*)d_ws;
    const size_t R = 67108864;                 // 64 MiB region
    float* ms_inp = (float*)ws;                // [32764, 512]  (later reused as y)
    float* msbuf  = (float*)(ws + R);          // [32768, 512]
    float* csum   = (float*)(ws + 2 * R);      // [4, 64, 512]
    float* y      = ms_inp;                    // reuse after scan consumes ms_inp

    // 1) av GEMM + NRU combine -> ms_inp
    gemm_av_mfma<<<dim3(256, 16), 256, 0, stream>>>(x, Wav, bav, ms_inp);
    // 2-4) chunked cumsum -> ms
    scan_pass1<<<dim3(64, B_SZ), 256, 0, stream>>>(ms_inp, csum);
    scan_pass2<<<8, 256, 0, stream>>>(csum);
    scan_pass3<<<dim3(64, B_SZ), 256, 0, stream>>>(ms_inp, csum, msbuf);
    // 5) SSM-in GEMM + GELU -> y  (reuses ms_inp region)
    gemm_go_mfma<<<dim3(256, 4), 256, 0, stream>>>(x, msbuf, Wgo, bgo, y);
    // 6) output GEMM + GLU -> out
    gemm_out_mfma<<<dim3(256, 8), 256, 0, stream>>>(y, Wout, bout, out);
}